// Round 8
// baseline (358.955 us; speedup 1.0000x reference)
//
#include <hip/hip_runtime.h>
#include <math.h>

// Problem dims (fixed)
#define NB 16
#define NV 12
#define NROWS 192          // NB*NV
#define DRAW 200704
#define KOUT 256
#define DFEAT 1024
#define NG 8
#define NCLS 40

// K1: 512 blocks = 256 K-chunks x 2 col-halves. KC=784 -> 25 steps of BK=32.
#define NCHUNK 256
#define KC 784

// per-LDS-buffer offsets (bytes): A 12 tiles x 2048 (1KB hi + 1KB lo), B 8 x 2048
#define ABASE 0
#define BBASE 24576
#define BUFSZ 40960        // x2 buffers = 81920 -> 2 blocks/CU

// workspace layout (bytes)
#define WS_SCORE 0                       // [192] f32
#define WS_PART  4096                    // [192 rows][256 chunks][256 cols] f32

typedef __attribute__((ext_vector_type(8))) short short8;
typedef __attribute__((ext_vector_type(4))) float f32x4;

// split x -> hi(bf16 trunc) + lo(bf16 trunc of exact residual); pack 4 elems
__device__ __forceinline__ void cvt4(float4 v, uint2& hi, uint2& lo) {
    unsigned b0 = __float_as_uint(v.x), b1 = __float_as_uint(v.y);
    unsigned b2 = __float_as_uint(v.z), b3 = __float_as_uint(v.w);
    hi.x = (b0 >> 16) | (b1 & 0xffff0000u);
    hi.y = (b2 >> 16) | (b3 & 0xffff0000u);
    float r0 = v.x - __uint_as_float(b0 & 0xffff0000u);
    float r1 = v.y - __uint_as_float(b1 & 0xffff0000u);
    float r2 = v.z - __uint_as_float(b2 & 0xffff0000u);
    float r3 = v.w - __uint_as_float(b3 & 0xffff0000u);
    lo.x = (__float_as_uint(r0) >> 16) | (__float_as_uint(r1) & 0xffff0000u);
    lo.y = (__float_as_uint(r2) >> 16) | (__float_as_uint(r3) & 0xffff0000u);
}

// issue step-S global loads into named reg buffers
#define K1_LOAD(DA, DB, S)                                                     \
  {                                                                            \
    const int koff = (S) * 32;                                                 \
    const float4 f4z = make_float4(0.f, 0.f, 0.f, 0.f);                        \
    _Pragma("unroll") for (int p = 0; p < 3; ++p) {                            \
      bool ok = aact[p] && (akq[p] * 4 + koff < KC);                           \
      DA[p] = ok ? *(const float4*)(aptr[p] + koff) : f4z;                     \
    }                                                                          \
    _Pragma("unroll") for (int q = 0; q < 8; ++q) {                            \
      int dd = bkh * 8 + q + koff;                                             \
      DB[q] = (dd < KC) ? bptr[(size_t)(koff + q) * KOUT] : 0.f;               \
    }                                                                          \
  }

// cvt regs -> LDS buffer WB (compile-time 0 or BUFSZ)
#define K1_WRITE(CA, CB, WB)                                                   \
  {                                                                            \
    _Pragma("unroll") for (int p = 0; p < 3; ++p) {                            \
      uint2 hi, lo; cvt4(CA[p], hi, lo);                                       \
      *(uint2*)(smem + (WB) + awoff[p]) = hi;                                  \
      *(uint2*)(smem + (WB) + awoff[p] + 1024) = lo;                           \
    }                                                                          \
    {                                                                          \
      uint2 h0, l0, h1, l1;                                                    \
      cvt4(make_float4(CB[0], CB[1], CB[2], CB[3]), h0, l0);                   \
      cvt4(make_float4(CB[4], CB[5], CB[6], CB[7]), h1, l1);                   \
      uint4 hv; hv.x = h0.x; hv.y = h0.y; hv.z = h1.x; hv.w = h1.y;            \
      uint4 lv; lv.x = l0.x; lv.y = l0.y; lv.z = l1.x; lv.w = l1.y;            \
      *(uint4*)(smem + (WB) + bwoff) = hv;                                     \
      *(uint4*)(smem + (WB) + bwoff + 1024) = lv;                              \
    }                                                                          \
  }

// fragment reads from buffer RB (interleaved per-tn) + 36 MFMAs
#define K1_MMA(RB)                                                             \
  {                                                                            \
    short8 ah[3], al[3];                                                       \
    _Pragma("unroll") for (int tm = 0; tm < 3; ++tm) {                         \
      int off = (RB) + ABASE + (wm * 3 + tm) * 2048 + aroff;                   \
      ah[tm] = *(const short8*)(smem + off);                                   \
      al[tm] = *(const short8*)(smem + off + 1024);                            \
    }                                                                          \
    _Pragma("unroll") for (int tn = 0; tn < 4; ++tn) {                         \
      int off = (RB) + BBASE + (wn * 4 + tn) * 2048 +                          \
                ((lane << 4) ^ ((tn & 1) << 6));                               \
      short8 bh = *(const short8*)(smem + off);                                \
      short8 bl = *(const short8*)(smem + off + 1024);                         \
      _Pragma("unroll") for (int tm = 0; tm < 3; ++tm) {                       \
        acc[tm][tn] = __builtin_amdgcn_mfma_f32_16x16x32_bf16(ah[tm], bh, acc[tm][tn], 0, 0, 0); \
        acc[tm][tn] = __builtin_amdgcn_mfma_f32_16x16x32_bf16(ah[tm], bl, acc[tm][tn], 0, 0, 0); \
        acc[tm][tn] = __builtin_amdgcn_mfma_f32_16x16x32_bf16(al[tm], bh, acc[tm][tn], 0, 0, 0); \
      }                                                                        \
    }                                                                          \
  }

// one K-step, dbuf, SINGLE barrier. Program order: issue loads(s+2), MMA on
// buf[s&1] (ds_reads first -> MFMA starts immediately), then cvt+write
// data(s+1) into the other buffer -- cvt VALU + ds_writes fill MFMA bubbles.
// Race-free: all reads of a buffer completed under the PREVIOUS step's
// lgkmcnt(0)+barrier before that buffer is rewritten one step later.
#define K1_STEP(CA, CB, NA, NB_, RB, WB, S, DOLOAD, DOWRITE)                   \
  {                                                                            \
    if (DOLOAD) K1_LOAD(NA, NB_, (S) + 2);                                     \
    K1_MMA(RB);                                                                \
    if (DOWRITE) K1_WRITE(CA, CB, WB);                                         \
    asm volatile("s_waitcnt lgkmcnt(0)" ::: "memory");                         \
    __builtin_amdgcn_sched_barrier(0);                                         \
    __builtin_amdgcn_s_barrier();                                              \
    __builtin_amdgcn_sched_barrier(0);                                         \
  }

// MFMA split-K/split-N GEMM. Co-XCD bid map: both col-halves of a chunk share
// bid%8 (same XCD L2 for A reuse). 8 waves 4(M)x2(N); wave owns 48x64 = 3x4
// fragments. bf16x3: acc += ah*bh + ah*bl + al*bh (f32 accumulate in MFMA).
__global__ __launch_bounds__(512, 4)
void k1_mfma(const float* __restrict__ raw, const float* __restrict__ W1,
             const int* __restrict__ vnum, float* __restrict__ part)
{
    __shared__ __align__(16) char smem[2 * BUFSZ];
    const int t = threadIdx.x;
    const int g8 = blockIdx.x & 7;
    const int i8 = blockIdx.x >> 3;
    const int c = g8 * 32 + (i8 >> 1);
    const int colbase = (i8 & 1) * 128;
    const int d0 = c * KC;

    // ---- A staging geometry: 3 passes, idx=p*512+t: row=idx>>3, kq=idx&7 ----
    int akq[3];
    bool aact[3];
    const float* aptr[3];
    int awoff[3];
#pragma unroll
    for (int p = 0; p < 3; ++p) {
        int idx = p * 512 + t;
        int row = idx >> 3, kq = idx & 7;
        akq[p] = kq;
        aact[p] = (row % NV) < vnum[row / NV];
        aptr[p] = raw + (size_t)row * DRAW + d0 + kq * 4;
        int off = ABASE + (row >> 4) * 2048 + (((row & 15) + ((kq >> 1) << 4)) << 4) + ((kq & 1) << 3);
        off ^= ((kq >> 1) & 1) << 6;
        awoff[p] = off;
    }
    // ---- B staging: col = t&127 (within half), bkh = t>>7 (8 k each) ----
    const int bcol = t & 127;
    const int bkh = t >> 7;
    const float* bptr = W1 + (size_t)(d0 + bkh * 8) * KOUT + colbase + bcol;
    const int bTN = bcol >> 4;
    int bwoff = BBASE + bTN * 2048 + (((bcol & 15) + (bkh << 4)) << 4);
    bwoff ^= (bTN & 1) << 6;

    // wave/fragment geometry
    const int lane = t & 63;
    const int wave = t >> 6;
    const int wm = wave >> 1, wn = wave & 1;
    const int aroff = (lane << 4) ^ (((lane >> 4) & 1) << 6);

    f32x4 acc[3][4];
#pragma unroll
    for (int i = 0; i < 3; ++i)
#pragma unroll
        for (int j = 0; j < 4; ++j) acc[i][j] = (f32x4){0.f, 0.f, 0.f, 0.f};

    float4 A0[3], A1[3];
    float B0r[8], B1r[8];
    // prologue: data0 -> buf0; data1 -> regs(A1)
    K1_LOAD(A0, B0r, 0);
    K1_WRITE(A0, B0r, 0);
    K1_LOAD(A1, B1r, 1);
    asm volatile("s_waitcnt lgkmcnt(0)" ::: "memory");
    __builtin_amdgcn_s_barrier();
    __builtin_amdgcn_sched_barrier(0);

    // steps 0..21 in pairs; 22 (last load), 23 (last write), 24 (MMA only).
    // step s: reads buf[s&1], writes data(s+1) -> buf[(s+1)&1],
    //         consumes regs(data s+1), loads regs(data s+2).
#pragma unroll 1
    for (int sp = 0; sp < 11; ++sp) {
        K1_STEP(A1, B1r, A0, B0r, 0, BUFSZ, 2 * sp, 1, 1);
        K1_STEP(A0, B0r, A1, B1r, BUFSZ, 0, 2 * sp + 1, 1, 1);
    }
    K1_STEP(A1, B1r, A0, B0r, 0, BUFSZ, 22, 1, 1);
    K1_STEP(A0, B0r, A1, B1r, BUFSZ, 0, 23, 0, 1);
    K1_STEP(A1, B1r, A0, B0r, 0, BUFSZ, 24, 0, 0);

    // ---- epilogue: part[row][chunk][col]; C/D: col=lane&15, row=(lane>>4)*4+r
#pragma unroll
    for (int tm = 0; tm < 3; ++tm) {
        int row0 = wm * 48 + tm * 16 + ((lane >> 4) << 2);
#pragma unroll
        for (int tn = 0; tn < 4; ++tn) {
            int col = colbase + wn * 64 + tn * 16 + (lane & 15);
            f32x4 a = acc[tm][tn];
#pragma unroll
            for (int r = 0; r < 4; ++r)
                part[((size_t)(row0 + r) * NCHUNK + c) * KOUT + col] = a[r];
        }
    }
}

// fused 256-chunk reduce + score head. One block per row; part[row] is a
// CONTIGUOUS 256KB stream -> coalesced.
__global__ __launch_bounds__(1024)
void k2_score(const float* __restrict__ part, const float* __restrict__ b1,
              const float* __restrict__ W2, const float* __restrict__ b2,
              float* __restrict__ score)
{
    const int row = blockIdx.x, t = threadIdx.x;
    const int col = t & 255, cg = t >> 8;
    __shared__ float red[4][KOUT];
    __shared__ float r2[4];
    const float* p = part + ((size_t)row * NCHUNK + cg * 64) * KOUT + col;
    float s = 0.f;
#pragma unroll 8
    for (int i = 0; i < 64; ++i) s += p[(size_t)i * KOUT];
    red[cg][col] = s;
    __syncthreads();
    if (t < 256) {
        float v = red[0][col] + red[1][col] + red[2][col] + red[3][col];
        float h = fmaxf(v + b1[col], 0.f) * W2[col];
        for (int o = 32; o > 0; o >>= 1) h += __shfl_down(h, o, 64);
        if ((t & 63) == 0) r2[t >> 6] = h;
    }
    __syncthreads();
    if (t == 0) {
        float sm = r2[0] + r2[1] + r2[2] + r2[3];
        float sraw = fmaxf(sm + b2[0], 0.f);
        score[row] = 1.f / (1.f + expf(-tanhf(fabsf(sraw))));
    }
}

// fused tail: binning->coeff->desc->3-layer classifier. One block per sample.
// (verified R4)
__global__ __launch_bounds__(512)
void k5f(const float* __restrict__ score, const int* __restrict__ vnum,
         const float* __restrict__ fv,
         const float* __restrict__ Wf1, const float* __restrict__ bf1,
         const float* __restrict__ Wf2, const float* __restrict__ bf2,
         const float* __restrict__ Wl,  const float* __restrict__ bl,
         float* __restrict__ out)
{
    const int n = blockIdx.x, t = threadIdx.x;
    __shared__ float coeffL[NV], descL[DFEAT], z1L[512], z2L[256];
    __shared__ float wsum[NG], wt[NG], outred[8][NCLS];
    __shared__ int cnt[NG];
    __shared__ float wtotS;
    if (t < NG) { cnt[t] = 0; wsum[t] = 0.f; }
    __syncthreads();
    const int vn = vnum[n];
    const bool act = (t < NV) && (t < vn);
    float sc = 0.f; int b = 0;
    if (act) {
        sc = score[n * NV + t];
        b = (int)floorf(sc * 8.f); b = b < 0 ? 0 : (b > 7 ? 7 : b);
        atomicAdd(&cnt[b], 1);
    }
    __syncthreads();
    if (act) atomicAdd(&wsum[b], ceilf(sc * (float)cnt[b]));
    __syncthreads();
    if (t < NG) wt[t] = (cnt[t] > 0) ? wsum[t] / (float)cnt[t] : 0.f;
    __syncthreads();
    if (t == 0) { float x = 0.f; for (int g = 0; g < NG; ++g) x += wt[g]; wtotS = x; }
    __syncthreads();
    if (t < NV) coeffL[t] = act ? wt[b] / ((float)cnt[b] * wtotS) : 0.f;
    __syncthreads();
#pragma unroll
    for (int p = 0; p < 2; ++p) {
        int d = t + p * 512;
        float a = 0.f;
#pragma unroll
        for (int v = 0; v < NV; ++v)
            a = fmaf(coeffL[v], fv[((size_t)n * NV + v) * DFEAT + d], a);
        descL[d] = a;
    }
    __syncthreads();
    {
        float a = 0.f;
#pragma unroll 8
        for (int d = 0; d < DFEAT; ++d)
            a = fmaf(descL[d], Wf1[(size_t)d * 512 + t], a);
        z1L[t] = fmaxf(a + bf1[t], 0.f);
    }
    __syncthreads();
    if (t < 256) {
        float a = 0.f;
#pragma unroll 8
        for (int d = 0; d < 512; ++d)
            a = fmaf(z1L[d], Wf2[(size_t)d * 256 + t], a);
        z2L[t] = fmaxf(a + bf2[t], 0.f);
    }
    __syncthreads();
    if (t < 320) {
        int j = t % NCLS, seg = t / NCLS;
        float a = 0.f;
#pragma unroll
        for (int dd = 0; dd < 32; ++dd) {
            int d = seg * 32 + dd;
            a = fmaf(z2L[d], Wl[d * NCLS + j], a);
        }
        outred[seg][j] = a;
    }
    __syncthreads();
    if (t < NCLS) {
        float a = bl[t];
#pragma unroll
        for (int s8 = 0; s8 < 8; ++s8) a += outred[s8][t];
        out[n * NCLS + t] = a;
    }
}

extern "C" void kernel_launch(void* const* d_in, const int* in_sizes, int n_in,
                              void* d_out, int out_size, void* d_ws, size_t ws_size,
                              hipStream_t stream)
{
    const float* raw  = (const float*)d_in[0];
    const float* fv   = (const float*)d_in[1];
    const int*   vnum = (const int*)d_in[2];
    const float* W1   = (const float*)d_in[3];
    const float* b1   = (const float*)d_in[4];
    const float* W2   = (const float*)d_in[5];
    const float* b2   = (const float*)d_in[6];
    const float* Wf1  = (const float*)d_in[7];
    const float* bf1  = (const float*)d_in[8];
    const float* Wf2  = (const float*)d_in[9];
    const float* bf2  = (const float*)d_in[10];
    const float* Wl   = (const float*)d_in[11];
    const float* bl   = (const float*)d_in[12];
    float* out = (float*)d_out;
    char* ws = (char*)d_ws;
    float* score = (float*)(ws + WS_SCORE);
    float* part  = (float*)(ws + WS_PART);

    k1_mfma<<<2 * NCHUNK, 512, 0, stream>>>(raw, W1, vnum, part);
    k2_score<<<NROWS, 1024, 0, stream>>>(part, b1, W2, b2, score);
    k5f<<<NB, 512, 0, stream>>>(score, vnum, fv, Wf1, bf1, Wf2, bf2, Wl, bl, out);
}

// Round 9
// 207.804 us; speedup vs baseline: 1.7274x; 1.7274x over previous
//
#include <hip/hip_runtime.h>
#include <math.h>

// Problem dims (fixed)
#define NB 16
#define NV 12
#define NROWS 192          // NB*NV
#define DRAW 200704
#define KOUT 256
#define DFEAT 1024
#define NG 8
#define NCLS 40

// K1: 512 blocks = 256 K-chunks x 2 col-halves. KC=784 -> 25 steps of BK=32
// (step 24: only k<16 valid).
#define NCHUNK 256
#define KC 784

// LDS (bytes), single buffer 40960: A 12 tiles x 2048 (1KB hi + 1KB lo), B 8 x 2048
#define ABASE 0
#define BBASE 24576

// workspace layout (bytes)
#define WS_P     0                       // [192][256] f32 (atomic accumulator)
#define WS_SCORE 196608                  // [192] f32

typedef __attribute__((ext_vector_type(8))) short short8;
typedef __attribute__((ext_vector_type(4))) float f32x4;

__global__ __launch_bounds__(256) void k0_zero(float* __restrict__ P) {
    P[blockIdx.x * 256 + threadIdx.x] = 0.f;
}

// split x -> hi(bf16 trunc) + lo(bf16 trunc of exact residual); pack 4 elems.
// v_perm-based packing: 12 VALU ops (was 20).
__device__ __forceinline__ void cvt4(float4 v, uint2& hi, uint2& lo) {
    unsigned b0 = __float_as_uint(v.x), b1 = __float_as_uint(v.y);
    unsigned b2 = __float_as_uint(v.z), b3 = __float_as_uint(v.w);
    hi.x = __builtin_amdgcn_perm(b1, b0, 0x07060302u);
    hi.y = __builtin_amdgcn_perm(b3, b2, 0x07060302u);
    unsigned r0 = __float_as_uint(v.x - __uint_as_float(b0 & 0xffff0000u));
    unsigned r1 = __float_as_uint(v.y - __uint_as_float(b1 & 0xffff0000u));
    unsigned r2 = __float_as_uint(v.z - __uint_as_float(b2 & 0xffff0000u));
    unsigned r3 = __float_as_uint(v.w - __uint_as_float(b3 & 0xffff0000u));
    lo.x = __builtin_amdgcn_perm(r1, r0, 0x07060302u);
    lo.y = __builtin_amdgcn_perm(r3, r2, 0x07060302u);
}

// main-step load: NO guards, literal offsets. A: 3 dwordx4 (imm-folded).
// B: one pointer bump + 8 dwords (q*KOUT literal).
#define K1_LOADM(DA, DB, S)                                                    \
  {                                                                            \
    _Pragma("unroll") for (int p = 0; p < 3; ++p)                              \
      DA[p] = *(const float4*)(aptr[p] + (S) * 32);                            \
    const float* bp = bptr + (size_t)((S) * 32) * KOUT;                        \
    _Pragma("unroll") for (int q = 0; q < 8; ++q)                              \
      DB[q] = bp[q * KOUT];                                                    \
  }

// tail-step load (step 24, only k<16 valid): pre-clamped safe pointers;
// A per-lane select, B wave-uniform branch (bkh<2).
#define K1_LOADT(DA, DB)                                                       \
  {                                                                            \
    const float4 f4z = make_float4(0.f, 0.f, 0.f, 0.f);                        \
    _Pragma("unroll") for (int p = 0; p < 3; ++p) {                            \
      float4 v = *(const float4*)(aptrT[p]);                                   \
      DA[p] = aokT[p] ? v : f4z;                                               \
    }                                                                          \
    if (bokT) {                                                                \
      const float* bp = bptr + (size_t)768 * KOUT;                             \
      _Pragma("unroll") for (int q = 0; q < 8; ++q) DB[q] = bp[q * KOUT];      \
    } else {                                                                   \
      _Pragma("unroll") for (int q = 0; q < 8; ++q) DB[q] = 0.f;               \
    }                                                                          \
  }

// cvt regs -> LDS (single buffer)
#define K1_WRITE(CA, CB)                                                       \
  {                                                                            \
    _Pragma("unroll") for (int p = 0; p < 3; ++p) {                            \
      uint2 hi, lo; cvt4(CA[p], hi, lo);                                       \
      *(uint2*)(smem + awoff[p]) = hi;                                         \
      *(uint2*)(smem + awoff[p] + 1024) = lo;                                  \
    }                                                                          \
    {                                                                          \
      uint2 h0, l0, h1, l1;                                                    \
      cvt4(make_float4(CB[0], CB[1], CB[2], CB[3]), h0, l0);                   \
      cvt4(make_float4(CB[4], CB[5], CB[6], CB[7]), h1, l1);                   \
      uint4 hv; hv.x = h0.x; hv.y = h0.y; hv.z = h1.x; hv.w = h1.y;            \
      uint4 lv; lv.x = l0.x; lv.y = l0.y; lv.z = l1.x; lv.w = l1.y;            \
      *(uint4*)(smem + bwoff) = hv;                                            \
      *(uint4*)(smem + bwoff + 1024) = lv;                                     \
    }                                                                          \
  }

// fragment reads + 36 MFMAs (bf16x3)
#define K1_MMA()                                                               \
  {                                                                            \
    short8 ah[3], al[3];                                                       \
    _Pragma("unroll") for (int tm = 0; tm < 3; ++tm) {                         \
      int off = ABASE + (wm * 3 + tm) * 2048 + aroff;                          \
      ah[tm] = *(const short8*)(smem + off);                                   \
      al[tm] = *(const short8*)(smem + off + 1024);                            \
    }                                                                          \
    _Pragma("unroll") for (int tn = 0; tn < 4; ++tn) {                         \
      int off = BBASE + (wn * 4 + tn) * 2048 + ((lane << 4) ^ ((tn & 1) << 6));\
      short8 bh = *(const short8*)(smem + off);                                \
      short8 bl = *(const short8*)(smem + off + 1024);                         \
      _Pragma("unroll") for (int tm = 0; tm < 3; ++tm) {                       \
        acc[tm][tn] = __builtin_amdgcn_mfma_f32_16x16x32_bf16(ah[tm], bh, acc[tm][tn], 0, 0, 0); \
        acc[tm][tn] = __builtin_amdgcn_mfma_f32_16x16x32_bf16(ah[tm], bl, acc[tm][tn], 0, 0, 0); \
        acc[tm][tn] = __builtin_amdgcn_mfma_f32_16x16x32_bf16(al[tm], bh, acc[tm][tn], 0, 0, 0); \
      }                                                                        \
    }                                                                          \
  }

// one K-step, R4 discipline: raw top barrier (no vmcnt drain), issue next
// loads (stay in flight through MFMA), cvt+write cur (counted vmcnt wait),
// lgkm+barrier, MMA.
#define K1_STEP_BODY(LOADSTMT, CA, CB)                                         \
  {                                                                            \
    __builtin_amdgcn_sched_barrier(0);                                         \
    __builtin_amdgcn_s_barrier();                                              \
    __builtin_amdgcn_sched_barrier(0);                                         \
    LOADSTMT;                                                                  \
    K1_WRITE(CA, CB);                                                          \
    asm volatile("s_waitcnt lgkmcnt(0)" ::: "memory");                         \
    __builtin_amdgcn_s_barrier();                                              \
    __builtin_amdgcn_sched_barrier(0);                                         \
    K1_MMA();                                                                  \
  }

// MFMA split-K/split-N GEMM, atomic-accumulate into P[192][256].
// Co-XCD bid map: both col-halves of a chunk share bid%8 (same XCD L2).
// 8 waves 4(M)x2(N); wave owns 48 rows x 64 cols = 3x4 fragments.
// Inactive-view rows load real (unused) data -> garbage P rows, masked at
// binning. bf16x3: acc += ah*bh + ah*bl + al*bh.
__global__ __launch_bounds__(512, 4)
void k1_mfma(const float* __restrict__ raw, const float* __restrict__ W1,
             float* __restrict__ P)
{
    __shared__ __align__(16) char smem[40960];
    const int t = threadIdx.x;
    const int g8 = blockIdx.x & 7;
    const int i8 = blockIdx.x >> 3;
    const int c = g8 * 32 + (i8 >> 1);
    const int colbase = (i8 & 1) * 128;
    const int d0 = c * KC;

    // ---- A staging geometry: 3 passes, idx=p*512+t: row=idx>>3, kq=idx&7 ----
    const float* aptr[3];
    const float* aptrT[3];
    bool aokT[3];
    int awoff[3];
#pragma unroll
    for (int p = 0; p < 3; ++p) {
        int idx = p * 512 + t;
        int row = idx >> 3, kq = idx & 7;
        aptr[p] = raw + (size_t)row * DRAW + d0 + kq * 4;
        aokT[p] = (kq < 4);
        aptrT[p] = aptr[p] + (aokT[p] ? 768 : 0);   // safe addr for tail step
        int off = ABASE + (row >> 4) * 2048 + (((row & 15) + ((kq >> 1) << 4)) << 4) + ((kq & 1) << 3);
        off ^= ((kq >> 1) & 1) << 6;
        awoff[p] = off;
    }
    // ---- B staging: col = t&127 (within half), bkh = t>>7 (8 k each) ----
    const int bcol = t & 127;
    const int bkh = t >> 7;
    const float* bptr = W1 + (size_t)(d0 + bkh * 8) * KOUT + colbase + bcol;
    const bool bokT = (bkh < 2);                    // wave-uniform
    const int bTN = bcol >> 4;
    int bwoff = BBASE + bTN * 2048 + (((bcol & 15) + (bkh << 4)) << 4);
    bwoff ^= (bTN & 1) << 6;

    // wave/fragment geometry
    const int lane = t & 63;
    const int wave = t >> 6;
    const int wm = wave >> 1, wn = wave & 1;
    const int aroff = (lane << 4) ^ (((lane >> 4) & 1) << 6);

    f32x4 acc[3][4];
#pragma unroll
    for (int i = 0; i < 3; ++i)
#pragma unroll
        for (int j = 0; j < 4; ++j) acc[i][j] = (f32x4){0.f, 0.f, 0.f, 0.f};

    float4 A0[3], A1[3];
    float B0r[8], B1r[8];
    K1_LOADM(A0, B0r, 0);

    // steps 0..21 in pairs (loads 1..22), 22 (loads 23), 23 (tail load 24), 24.
#pragma unroll 1
    for (int sp = 0; sp < 11; ++sp) {
        K1_STEP_BODY(K1_LOADM(A1, B1r, 2 * sp + 1), A0, B0r);
        K1_STEP_BODY(K1_LOADM(A0, B0r, 2 * sp + 2), A1, B1r);
    }
    K1_STEP_BODY(K1_LOADM(A1, B1r, 23), A0, B0r);   // step 22
    K1_STEP_BODY(K1_LOADT(A0, B0r), A1, B1r);       // step 23
    K1_STEP_BODY(, A0, B0r);                        // step 24

    // ---- epilogue: atomic accumulate; C/D: col=lane&15, row=(lane>>4)*4+r ----
#pragma unroll
    for (int tm = 0; tm < 3; ++tm) {
        int row0 = wm * 48 + tm * 16 + ((lane >> 4) << 2);
#pragma unroll
        for (int tn = 0; tn < 4; ++tn) {
            int col = colbase + wn * 64 + tn * 16 + (lane & 15);
            f32x4 a = acc[tm][tn];
#pragma unroll
            for (int r = 0; r < 4; ++r)
                atomicAdd(&P[(size_t)(row0 + r) * KOUT + col], a[r]);
        }
    }
}

// per-row score: h=relu(P+b1); sraw=relu(h.W2+b2); score=sigmoid(tanh(|.|))
__global__ __launch_bounds__(256)
void k2b(const float* __restrict__ P, const float* __restrict__ b1,
         const float* __restrict__ W2, const float* __restrict__ b2,
         float* __restrict__ score)
{
    const int row = blockIdx.x, t = threadIdx.x;
    float s = P[(size_t)row * KOUT + t];
    float val = fmaxf(s + b1[t], 0.f) * W2[t];
    for (int o = 32; o > 0; o >>= 1) val += __shfl_down(val, o, 64);
    __shared__ float red[4];
    if ((t & 63) == 0) red[t >> 6] = val;
    __syncthreads();
    if (t == 0) {
        float sm = red[0] + red[1] + red[2] + red[3];
        float sraw = fmaxf(sm + b2[0], 0.f);
        score[row] = 1.f / (1.f + expf(-tanhf(fabsf(sraw))));
    }
}

// fused tail: binning->coeff->desc->3-layer classifier. One block per sample.
// (verified R4)
__global__ __launch_bounds__(512)
void k5f(const float* __restrict__ score, const int* __restrict__ vnum,
         const float* __restrict__ fv,
         const float* __restrict__ Wf1, const float* __restrict__ bf1,
         const float* __restrict__ Wf2, const float* __restrict__ bf2,
         const float* __restrict__ Wl,  const float* __restrict__ bl,
         float* __restrict__ out)
{
    const int n = blockIdx.x, t = threadIdx.x;
    __shared__ float coeffL[NV], descL[DFEAT], z1L[512], z2L[256];
    __shared__ float wsum[NG], wt[NG], outred[8][NCLS];
    __shared__ int cnt[NG];
    __shared__ float wtotS;
    if (t < NG) { cnt[t] = 0; wsum[t] = 0.f; }
    __syncthreads();
    const int vn = vnum[n];
    const bool act = (t < NV) && (t < vn);
    float sc = 0.f; int b = 0;
    if (act) {
        sc = score[n * NV + t];
        b = (int)floorf(sc * 8.f); b = b < 0 ? 0 : (b > 7 ? 7 : b);
        atomicAdd(&cnt[b], 1);
    }
    __syncthreads();
    if (act) atomicAdd(&wsum[b], ceilf(sc * (float)cnt[b]));
    __syncthreads();
    if (t < NG) wt[t] = (cnt[t] > 0) ? wsum[t] / (float)cnt[t] : 0.f;
    __syncthreads();
    if (t == 0) { float x = 0.f; for (int g = 0; g < NG; ++g) x += wt[g]; wtotS = x; }
    __syncthreads();
    if (t < NV) coeffL[t] = act ? wt[b] / ((float)cnt[b] * wtotS) : 0.f;
    __syncthreads();
#pragma unroll
    for (int p = 0; p < 2; ++p) {
        int d = t + p * 512;
        float a = 0.f;
#pragma unroll
        for (int v = 0; v < NV; ++v)
            a = fmaf(coeffL[v], fv[((size_t)n * NV + v) * DFEAT + d], a);
        descL[d] = a;
    }
    __syncthreads();
    {
        float a = 0.f;
#pragma unroll 8
        for (int d = 0; d < DFEAT; ++d)
            a = fmaf(descL[d], Wf1[(size_t)d * 512 + t], a);
        z1L[t] = fmaxf(a + bf1[t], 0.f);
    }
    __syncthreads();
    if (t < 256) {
        float a = 0.f;
#pragma unroll 8
        for (int d = 0; d < 512; ++d)
            a = fmaf(z1L[d], Wf2[(size_t)d * 256 + t], a);
        z2L[t] = fmaxf(a + bf2[t], 0.f);
    }
    __syncthreads();
    if (t < 320) {
        int j = t % NCLS, seg = t / NCLS;
        float a = 0.f;
#pragma unroll
        for (int dd = 0; dd < 32; ++dd) {
            int d = seg * 32 + dd;
            a = fmaf(z2L[d], Wl[d * NCLS + j], a);
        }
        outred[seg][j] = a;
    }
    __syncthreads();
    if (t < NCLS) {
        float a = bl[t];
#pragma unroll
        for (int s8 = 0; s8 < 8; ++s8) a += outred[s8][t];
        out[n * NCLS + t] = a;
    }
}

extern "C" void kernel_launch(void* const* d_in, const int* in_sizes, int n_in,
                              void* d_out, int out_size, void* d_ws, size_t ws_size,
                              hipStream_t stream)
{
    const float* raw  = (const float*)d_in[0];
    const float* fv   = (const float*)d_in[1];
    const int*   vnum = (const int*)d_in[2];
    const float* W1   = (const float*)d_in[3];
    const float* b1   = (const float*)d_in[4];
    const float* W2   = (const float*)d_in[5];
    const float* b2   = (const float*)d_in[6];
    const float* Wf1  = (const float*)d_in[7];
    const float* bf1  = (const float*)d_in[8];
    const float* Wf2  = (const float*)d_in[9];
    const float* bf2  = (const float*)d_in[10];
    const float* Wl   = (const float*)d_in[11];
    const float* bl   = (const float*)d_in[12];
    float* out = (float*)d_out;
    char* ws = (char*)d_ws;
    float* P     = (float*)(ws + WS_P);
    float* score = (float*)(ws + WS_SCORE);

    k0_zero<<<NROWS, 256, 0, stream>>>(P);
    k1_mfma<<<2 * NCHUNK, 512, 0, stream>>>(raw, W1, P);
    k2b<<<NROWS, 256, 0, stream>>>(P, b1, W2, b2, score);
    k5f<<<NB, 512, 0, stream>>>(score, vnum, fv, Wf1, bf1, Wf2, bf2, Wl, bl, out);
}